// Round 1
// baseline (381.268 us; speedup 1.0000x reference)
//
#include <hip/hip_runtime.h>
#include <hip/hip_bf16.h>

#define NN 16384
#define SIZE 256
#define DISTD 64
#define KNBR 16
#define HEADS 8
#define ATTND 32
#define HIDDEN 512
#define HA 256
#define EDGE 320

typedef __bf16 bf16;
typedef bf16 bf16x8 __attribute__((ext_vector_type(8)));
typedef float f32x4 __attribute__((ext_vector_type(4)));

// ---------------------------------------------------------------------------
// Generic bf16-MFMA GEMM: C[M,N] = act( relu_in?(A)[M,K] @ B[K,N] + bias + resid )
// M % 64 == 0, N % 64 == 0, K % 32 == 0. A,B,C fp32 row-major; compute bf16.
// ---------------------------------------------------------------------------
template<bool RELU_IN, bool BIAS, bool RELU_OUT, bool RESID>
__global__ __launch_bounds__(256) void gemm_kernel(
    const float* __restrict__ A, const float* __restrict__ B,
    const float* __restrict__ bias, const float* __restrict__ resid,
    float* __restrict__ C, int M, int N, int K)
{
    __shared__ bf16 As[64][40];   // [row][k]  (pad 32->40 to spread banks)
    __shared__ bf16 Bs[64][40];   // [col][k]  (B staged transposed)

    const int t = threadIdx.x;
    const int w = t >> 6;          // wave 0..3
    const int l = t & 63;          // lane
    const int bm = blockIdx.y * 64;
    const int bn = blockIdx.x * 64;

    f32x4 acc[4] = {};

    const int ar = t >> 2;         // 0..63 (A row)
    const int ac = (t & 3) * 8;    // 0..24 (A k-col)
    const int br = t >> 3;         // 0..31 (B k-row)
    const int bc = (t & 7) * 8;    // 0..56 (B col)

    for (int k0 = 0; k0 < K; k0 += 32) {
        const float* ap = A + (long)(bm + ar) * K + k0 + ac;
        #pragma unroll
        for (int i = 0; i < 8; ++i) {
            float v = ap[i];
            if (RELU_IN) v = fmaxf(v, 0.f);
            As[ar][ac + i] = (bf16)v;
        }
        const float* bp = B + (long)(k0 + br) * N + bn + bc;
        #pragma unroll
        for (int i = 0; i < 8; ++i) {
            Bs[bc + i][br] = (bf16)bp[i];
        }
        __syncthreads();

        bf16x8 afrag = *(const bf16x8*)&As[16 * w + (l & 15)][(l >> 4) * 8];
        #pragma unroll
        for (int nn = 0; nn < 4; ++nn) {
            bf16x8 bfrag = *(const bf16x8*)&Bs[nn * 16 + (l & 15)][(l >> 4) * 8];
            acc[nn] = __builtin_amdgcn_mfma_f32_16x16x32_bf16(afrag, bfrag, acc[nn], 0, 0, 0);
        }
        __syncthreads();
    }

    #pragma unroll
    for (int nn = 0; nn < 4; ++nn) {
        #pragma unroll
        for (int i = 0; i < 4; ++i) {
            int row = bm + 16 * w + (l >> 4) * 4 + i;
            int col = bn + nn * 16 + (l & 15);
            float v = acc[nn][i];
            if (BIAS) v += bias[col];
            if (RESID) v += resid[(long)row * N + col];
            if (RELU_OUT) v = fmaxf(v, 0.f);
            C[(long)row * N + col] = v;
        }
    }
}

// ---------------------------------------------------------------------------
// Wqp[c, h*64+d] = sum_a Wq[c, h*32+a] * Wk[256+d, h*32+a]    (256 x 512)
// ---------------------------------------------------------------------------
__global__ __launch_bounds__(256) void make_wqp(const float* __restrict__ Wq,
                                                const float* __restrict__ Wk,
                                                float* __restrict__ Wqp)
{
    int idx = blockIdx.x * 256 + threadIdx.x;  // 0..131071
    int c  = idx >> 9;
    int hd = idx & 511;
    int h = hd >> 6, d = hd & 63;
    const float* wq  = Wq + (long)c * HA + h * 32;
    const float* wkb = Wk + (long)(256 + d) * HA + h * 32;
    float s = 0.f;
    #pragma unroll
    for (int a = 0; a < 32; ++a) s += wq[a] * wkb[a];
    Wqp[idx] = s;
}

__global__ __launch_bounds__(256) void make_bqp(const float* __restrict__ bq,
                                                const float* __restrict__ Wk,
                                                float* __restrict__ bqp)
{
    int hd = blockIdx.x * 256 + threadIdx.x;  // 0..511
    int h = hd >> 6, d = hd & 63;
    float s = 0.f;
    #pragma unroll
    for (int a = 0; a < 32; ++a) s += bq[h * 32 + a] * Wk[(long)(256 + d) * HA + h * 32 + a];
    bqp[hd] = s;
}

// ---------------------------------------------------------------------------
// Attention: one block (256 threads) per node.
//  scores[h,j] = (q.localK[s_j] + dist[j].qproj[h]) * scale   (bk dropped: softmax-invariant)
//  o[t] = bv[t] + sum_j attn[h,j]*localV[s_j][t] + sum_d wd[h,d]*WvBot[d,t]
// ---------------------------------------------------------------------------
__global__ __launch_bounds__(256) void attn_kernel(
    const float* __restrict__ q,        // [NN, 256]
    const float* __restrict__ qproj,    // [NN, 512]  (h*64+d)
    const float* __restrict__ localK,   // [NN, 256]
    const float* __restrict__ localV,   // [NN, 256]
    const float* __restrict__ dist,     // [NN, 16, 64]
    const int*   __restrict__ structure,// [NN, 16]
    const float* __restrict__ Wv,       // [320, 256] (rows 256.. = WvBot)
    const float* __restrict__ bv,       // [256]
    float* __restrict__ o)              // [NN, 256]
{
    const int n = blockIdx.x;
    const int t = threadIdx.x;
    const int h = t >> 5, a = t & 31;

    __shared__ float q_s[256];
    __shared__ float qp_s[512];
    __shared__ float dist_s[16][64];
    __shared__ int   s_s[16];
    __shared__ float sc_loc[8][16];
    __shared__ float sc_dst[8][16];
    __shared__ float attn_s[8][16];
    __shared__ float wd_s[8][64];

    q_s[t] = q[(long)n * 256 + t];
    qp_s[t]       = qproj[(long)n * 512 + t];
    qp_s[t + 256] = qproj[(long)n * 512 + 256 + t];
    {
        const float* dp = dist + (long)n * (KNBR * DISTD);
        #pragma unroll
        for (int i = 0; i < 4; ++i) ((float*)dist_s)[t + 256 * i] = dp[t + 256 * i];
    }
    if (t < 16) s_s[t] = structure[(long)n * KNBR + t];
    __syncthreads();

    // local part of scores: reduce over a (32 lanes / head, 2 heads per wave)
    const float qv = q_s[t];
    #pragma unroll
    for (int j = 0; j < 16; ++j) {
        float p = qv * localK[(long)s_s[j] * 256 + t];
        p += __shfl_xor(p, 1);
        p += __shfl_xor(p, 2);
        p += __shfl_xor(p, 4);
        p += __shfl_xor(p, 8);
        p += __shfl_xor(p, 16);
        if (a == 0) sc_loc[h][j] = p;
    }
    // dist part of scores
    if (t < 128) {
        int h2 = t >> 4, j = t & 15;
        float s = 0.f;
        #pragma unroll
        for (int d = 0; d < 64; ++d) s += dist_s[j][d] * qp_s[h2 * 64 + d];
        sc_dst[h2][j] = s;
    }
    __syncthreads();

    // softmax over j (16-lane groups)
    if (t < 128) {
        int h2 = t >> 4, j = t & 15;
        const float scale = 0.17677669529663687f;  // 1/sqrt(32)
        float s = (sc_loc[h2][j] + sc_dst[h2][j]) * scale;
        float m = s;
        m = fmaxf(m, __shfl_xor(m, 1));
        m = fmaxf(m, __shfl_xor(m, 2));
        m = fmaxf(m, __shfl_xor(m, 4));
        m = fmaxf(m, __shfl_xor(m, 8));
        float e = __expf(s - m);
        float sum = e;
        sum += __shfl_xor(sum, 1);
        sum += __shfl_xor(sum, 2);
        sum += __shfl_xor(sum, 4);
        sum += __shfl_xor(sum, 8);
        attn_s[h2][j] = e / sum;
    }
    __syncthreads();

    // wd[h,d] = sum_j attn[h,j] * dist[j,d]   (512 outputs, 2 per thread)
    #pragma unroll
    for (int rep = 0; rep < 2; ++rep) {
        int idx = t + rep * 256;
        int h3 = idx >> 6, d = idx & 63;
        float s = 0.f;
        #pragma unroll
        for (int j = 0; j < 16; ++j) s += attn_s[h3][j] * dist_s[j][d];
        wd_s[h3][d] = s;
    }
    __syncthreads();

    // output
    float acc = bv[t];
    #pragma unroll
    for (int j = 0; j < 16; ++j)
        acc += attn_s[h][j] * localV[(long)s_s[j] * 256 + t];
    const float* WvBot = Wv + 256 * HA;
    #pragma unroll
    for (int d = 0; d < 64; ++d)
        acc += wd_s[h][d] * WvBot[(long)d * 256 + t];
    o[(long)n * 256 + t] = acc;
}

// ---------------------------------------------------------------------------
extern "C" void kernel_launch(void* const* d_in, const int* in_sizes, int n_in,
                              void* d_out, int out_size, void* d_ws, size_t ws_size,
                              hipStream_t stream)
{
    const float* features = (const float*)d_in[0];
    const float* dist     = (const float*)d_in[1];
    const int*   structure= (const int*)d_in[2];
    const float* W0 = (const float*)d_in[3];
    const float* b0 = (const float*)d_in[4];
    const float* W1 = (const float*)d_in[5];
    const float* b1 = (const float*)d_in[6];
    const float* W2 = (const float*)d_in[7];
    const float* b2 = (const float*)d_in[8];
    const float* Wq = (const float*)d_in[9];
    const float* bq = (const float*)d_in[10];
    const float* Wk = (const float*)d_in[11];
    // d_in[12] = bk : dropped (softmax-invariant per-head constant shift)
    const float* Wv = (const float*)d_in[13];
    const float* bv = (const float*)d_in[14];
    const float* Wo = (const float*)d_in[15];
    const float* bo = (const float*)d_in[16];
    float* out = (float*)d_out;

    float* ws = (float*)d_ws;
    float* bufA   = ws;                    // 16384*512  (H0 -> local -> o)
    float* bufB   = bufA + (long)NN * 512; // 16384*512  (H1 -> qproj)
    float* localK = bufB + (long)NN * 512; // 16384*256
    float* localV = localK + (long)NN * 256;
    float* qbuf   = localV + (long)NN * 256;
    float* Wqp    = qbuf + (long)NN * 256; // 256*512
    float* bqp    = Wqp + 256 * 512;       // 512

    dim3 blk(256);

    make_wqp<<<dim3(512), blk, 0, stream>>>(Wq, Wk, Wqp);
    make_bqp<<<dim3(2), blk, 0, stream>>>(bq, Wk, bqp);

    // MLP: H0 = relu(relu(features)@W0+b0); H1 = relu(H0@W1+b1); local = relu(H1@W2+b2)
    gemm_kernel<true,  true,  true,  false><<<dim3(HIDDEN/64, NN/64), blk, 0, stream>>>(
        features, W0, b0, nullptr, bufA, NN, HIDDEN, SIZE);
    gemm_kernel<false, true,  true,  false><<<dim3(HIDDEN/64, NN/64), blk, 0, stream>>>(
        bufA, W1, b1, nullptr, bufB, NN, HIDDEN, HIDDEN);
    gemm_kernel<false, true,  true,  false><<<dim3(SIZE/64, NN/64), blk, 0, stream>>>(
        bufB, W2, b2, nullptr, bufA, NN, SIZE, HIDDEN);

    // localK = local @ Wk[:256,:]; localV = local @ Wv[:256,:]
    gemm_kernel<false, false, false, false><<<dim3(SIZE/64, NN/64), blk, 0, stream>>>(
        bufA, Wk, nullptr, nullptr, localK, NN, HA, SIZE);
    gemm_kernel<false, false, false, false><<<dim3(SIZE/64, NN/64), blk, 0, stream>>>(
        bufA, Wv, nullptr, nullptr, localV, NN, HA, SIZE);

    // q = features@Wq + bq ; qproj = features@Wqp + bqp
    gemm_kernel<false, true,  false, false><<<dim3(SIZE/64, NN/64), blk, 0, stream>>>(
        features, Wq, bq, nullptr, qbuf, NN, HA, SIZE);
    gemm_kernel<false, true,  false, false><<<dim3(HIDDEN/64, NN/64), blk, 0, stream>>>(
        features, Wqp, bqp, nullptr, bufB, NN, 512, SIZE);

    // attention -> o (into bufA, local no longer needed)
    attn_kernel<<<dim3(NN), blk, 0, stream>>>(
        qbuf, bufB, localK, localV, dist, structure, Wv, bv, bufA);

    // out = o @ Wo + bo + features
    gemm_kernel<false, true,  false, true><<<dim3(SIZE/64, NN/64), blk, 0, stream>>>(
        bufA, Wo, bo, features, out, NN, SIZE, HA);
}

// Round 2
// 341.188 us; speedup vs baseline: 1.1175x; 1.1175x over previous
//
#include <hip/hip_runtime.h>
#include <hip/hip_bf16.h>

#define NN 16384
#define SIZE 256
#define DISTD 64
#define KNBR 16
#define HEADS 8
#define ATTND 32
#define HIDDEN 512
#define HA 256
#define EDGE 320

typedef __bf16 bf16;
typedef bf16 bf16x8 __attribute__((ext_vector_type(8)));
typedef float f32x4 __attribute__((ext_vector_type(4)));

// ---------------------------------------------------------------------------
// Generic bf16-MFMA GEMM: C[M,N] = act( relu_in?(A)[M,K] @ B[K,N] + bias + resid )
// M % 64 == 0, N % 64 == 0, K % 32 == 0. A,B fp32 row-major; compute bf16.
// C is OutT (float or bf16) with row stride ldc.
// ---------------------------------------------------------------------------
template<bool RELU_IN, bool BIAS, bool RELU_OUT, bool RESID, typename OutT>
__global__ __launch_bounds__(256) void gemm_kernel(
    const float* __restrict__ A, const float* __restrict__ B,
    const float* __restrict__ bias, const float* __restrict__ resid,
    OutT* __restrict__ C, int M, int N, int K, int ldc)
{
    __shared__ bf16 As[64][40];   // [row][k]  (pad 32->40 to spread banks)
    __shared__ bf16 Bs[64][40];   // [col][k]  (B staged transposed)

    const int t = threadIdx.x;
    const int w = t >> 6;          // wave 0..3
    const int l = t & 63;          // lane
    const int bm = blockIdx.y * 64;
    const int bn = blockIdx.x * 64;

    f32x4 acc[4] = {};

    const int ar = t >> 2;         // 0..63 (A row)
    const int ac = (t & 3) * 8;    // 0..24 (A k-col)
    const int br = t >> 3;         // 0..31 (B k-row)
    const int bc = (t & 7) * 8;    // 0..56 (B col)

    for (int k0 = 0; k0 < K; k0 += 32) {
        const float* ap = A + (long)(bm + ar) * K + k0 + ac;
        #pragma unroll
        for (int i = 0; i < 8; ++i) {
            float v = ap[i];
            if (RELU_IN) v = fmaxf(v, 0.f);
            As[ar][ac + i] = (bf16)v;
        }
        const float* bp = B + (long)(k0 + br) * N + bn + bc;
        #pragma unroll
        for (int i = 0; i < 8; ++i) {
            Bs[bc + i][br] = (bf16)bp[i];
        }
        __syncthreads();

        bf16x8 afrag = *(const bf16x8*)&As[16 * w + (l & 15)][(l >> 4) * 8];
        #pragma unroll
        for (int nn = 0; nn < 4; ++nn) {
            bf16x8 bfrag = *(const bf16x8*)&Bs[nn * 16 + (l & 15)][(l >> 4) * 8];
            acc[nn] = __builtin_amdgcn_mfma_f32_16x16x32_bf16(afrag, bfrag, acc[nn], 0, 0, 0);
        }
        __syncthreads();
    }

    #pragma unroll
    for (int nn = 0; nn < 4; ++nn) {
        #pragma unroll
        for (int i = 0; i < 4; ++i) {
            int row = bm + 16 * w + (l >> 4) * 4 + i;
            int col = bn + nn * 16 + (l & 15);
            float v = acc[nn][i];
            if (BIAS) v += bias[col];
            if (RESID) v += resid[(long)row * N + col];
            if (RELU_OUT) v = fmaxf(v, 0.f);
            C[(long)row * ldc + col] = (OutT)v;
        }
    }
}

// ---------------------------------------------------------------------------
// Wqp[c, h*64+d] = sum_a Wq[c, h*32+a] * Wk[256+d, h*32+a]    (256 x 512)
// ---------------------------------------------------------------------------
__global__ __launch_bounds__(256) void make_wqp(const float* __restrict__ Wq,
                                                const float* __restrict__ Wk,
                                                float* __restrict__ Wqp)
{
    int idx = blockIdx.x * 256 + threadIdx.x;  // 0..131071
    int c  = idx >> 9;
    int hd = idx & 511;
    int h = hd >> 6, d = hd & 63;
    const float* wq  = Wq + (long)c * HA + h * 32;
    const float* wkb = Wk + (long)(256 + d) * HA + h * 32;
    float s = 0.f;
    #pragma unroll
    for (int a = 0; a < 32; ++a) s += wq[a] * wkb[a];
    Wqp[idx] = s;
}

__global__ __launch_bounds__(256) void make_bqp(const float* __restrict__ bq,
                                                const float* __restrict__ Wk,
                                                float* __restrict__ bqp)
{
    int hd = blockIdx.x * 256 + threadIdx.x;  // 0..511
    int h = hd >> 6, d = hd & 63;
    float s = 0.f;
    #pragma unroll
    for (int a = 0; a < 32; ++a) s += bq[h * 32 + a] * Wk[(long)(256 + d) * HA + h * 32 + a];
    bqp[hd] = s;
}

// ---------------------------------------------------------------------------
// Attention: one block (256 threads) per node.
//  localKV[m][0:256] = K-row (bf16), localKV[m][256:512] = V-row (bf16)
//  scores[h,j] = (q.localK[s_j] + dist[j].qproj[h]) * scale   (bk dropped)
//  o[t] = bv[t] + sum_j attn[h,j]*localV[s_j][t] + sum_d wd[h,d]*WvBot[d,t]
// ---------------------------------------------------------------------------
__global__ __launch_bounds__(256) void attn_kernel(
    const float* __restrict__ q,        // [NN, 256] f32
    const float* __restrict__ qproj,    // [NN, 512] f32 (h*64+d)
    const bf16*  __restrict__ localKV,  // [NN, 512] bf16
    const float* __restrict__ dist,     // [NN, 16, 64]
    const int*   __restrict__ structure,// [NN, 16]
    const float* __restrict__ Wv,       // [320, 256] (rows 256.. = WvBot)
    const float* __restrict__ bv,       // [256]
    float* __restrict__ o)              // [NN, 256]
{
    const int n = blockIdx.x;
    const int t = threadIdx.x;
    const int h = t >> 5, a = t & 31;

    __shared__ float q_s[256];
    __shared__ float qp_s[512];
    __shared__ float dist_s[16][68];    // padded: 2-way banks (free)
    __shared__ int   s_s[16];
    __shared__ float sc_loc[8][16];
    __shared__ float sc_dst[8][16];
    __shared__ float attn_s[8][16];
    __shared__ float wd_s[8][64];

    q_s[t] = q[(long)n * 256 + t];
    qp_s[t]       = qproj[(long)n * 512 + t];
    qp_s[t + 256] = qproj[(long)n * 512 + 256 + t];
    {
        const float* dp = dist + (long)n * (KNBR * DISTD);
        #pragma unroll
        for (int i = 0; i < 4; ++i) {
            int e = t + 256 * i;
            dist_s[e >> 6][e & 63] = dp[e];
        }
    }
    if (t < 16) s_s[t] = structure[(long)n * KNBR + t];
    __syncthreads();

    // local part of scores: reduce over a (32 lanes / head, 2 heads per wave)
    const float qv = q_s[t];
    #pragma unroll
    for (int j = 0; j < 16; ++j) {
        float p = qv * (float)localKV[(long)s_s[j] * 512 + t];
        p += __shfl_xor(p, 1);
        p += __shfl_xor(p, 2);
        p += __shfl_xor(p, 4);
        p += __shfl_xor(p, 8);
        p += __shfl_xor(p, 16);
        if (a == 0) sc_loc[h][j] = p;
    }
    // dist part of scores
    if (t < 128) {
        int h2 = t >> 4, j = t & 15;
        float s = 0.f;
        #pragma unroll
        for (int d = 0; d < 64; ++d) s += dist_s[j][d] * qp_s[h2 * 64 + d];
        sc_dst[h2][j] = s;
    }
    __syncthreads();

    // softmax over j (16-lane groups)
    if (t < 128) {
        int h2 = t >> 4, j = t & 15;
        const float scale = 0.17677669529663687f;  // 1/sqrt(32)
        float s = (sc_loc[h2][j] + sc_dst[h2][j]) * scale;
        float m = s;
        m = fmaxf(m, __shfl_xor(m, 1));
        m = fmaxf(m, __shfl_xor(m, 2));
        m = fmaxf(m, __shfl_xor(m, 4));
        m = fmaxf(m, __shfl_xor(m, 8));
        float e = __expf(s - m);
        float sum = e;
        sum += __shfl_xor(sum, 1);
        sum += __shfl_xor(sum, 2);
        sum += __shfl_xor(sum, 4);
        sum += __shfl_xor(sum, 8);
        attn_s[h2][j] = e / sum;
    }
    __syncthreads();

    // wd[h,d] = sum_j attn[h,j] * dist[j,d]   (512 outputs, 2 per thread)
    #pragma unroll
    for (int rep = 0; rep < 2; ++rep) {
        int idx = t + rep * 256;
        int h3 = idx >> 6, d = idx & 63;
        float s = 0.f;
        #pragma unroll
        for (int j = 0; j < 16; ++j) s += attn_s[h3][j] * dist_s[j][d];
        wd_s[h3][d] = s;
    }
    __syncthreads();

    // output
    float acc = bv[t];
    #pragma unroll
    for (int j = 0; j < 16; ++j)
        acc += attn_s[h][j] * (float)localKV[(long)s_s[j] * 512 + 256 + t];
    const float* WvBot = Wv + 256 * HA;
    #pragma unroll
    for (int d = 0; d < 64; ++d)
        acc += wd_s[h][d] * WvBot[(long)d * 256 + t];
    o[(long)n * 256 + t] = acc;
}

// ---------------------------------------------------------------------------
extern "C" void kernel_launch(void* const* d_in, const int* in_sizes, int n_in,
                              void* d_out, int out_size, void* d_ws, size_t ws_size,
                              hipStream_t stream)
{
    const float* features = (const float*)d_in[0];
    const float* dist     = (const float*)d_in[1];
    const int*   structure= (const int*)d_in[2];
    const float* W0 = (const float*)d_in[3];
    const float* b0 = (const float*)d_in[4];
    const float* W1 = (const float*)d_in[5];
    const float* b1 = (const float*)d_in[6];
    const float* W2 = (const float*)d_in[7];
    const float* b2 = (const float*)d_in[8];
    const float* Wq = (const float*)d_in[9];
    const float* bq = (const float*)d_in[10];
    const float* Wk = (const float*)d_in[11];
    // d_in[12] = bk : dropped (softmax-invariant per-head constant shift)
    const float* Wv = (const float*)d_in[13];
    const float* bv = (const float*)d_in[14];
    const float* Wo = (const float*)d_in[15];
    const float* bo = (const float*)d_in[16];
    float* out = (float*)d_out;

    float* ws = (float*)d_ws;
    float* bufA   = ws;                    // 16384*512 f32 (H0 -> local -> o)
    float* bufB   = bufA + (long)NN * 512; // 16384*512 f32 (H1 -> qproj)
    float* qbuf   = bufB + (long)NN * 512; // 16384*256 f32
    float* Wqp    = qbuf + (long)NN * 256; // 256*512
    float* bqp    = Wqp + 256 * 512;       // 512
    bf16*  localKV= (bf16*)(bqp + 512);    // 16384*512 bf16 (K|V interleaved)

    dim3 blk(256);

    make_wqp<<<dim3(512), blk, 0, stream>>>(Wq, Wk, Wqp);
    make_bqp<<<dim3(2), blk, 0, stream>>>(bq, Wk, bqp);

    // MLP: H0 = relu(relu(features)@W0+b0); H1 = relu(H0@W1+b1); local = relu(H1@W2+b2)
    gemm_kernel<true,  true,  true,  false, float><<<dim3(HIDDEN/64, NN/64), blk, 0, stream>>>(
        features, W0, b0, nullptr, bufA, NN, HIDDEN, SIZE, HIDDEN);
    gemm_kernel<false, true,  true,  false, float><<<dim3(HIDDEN/64, NN/64), blk, 0, stream>>>(
        bufA, W1, b1, nullptr, bufB, NN, HIDDEN, HIDDEN, HIDDEN);
    gemm_kernel<false, true,  true,  false, float><<<dim3(SIZE/64, NN/64), blk, 0, stream>>>(
        bufB, W2, b2, nullptr, bufA, NN, SIZE, HIDDEN, SIZE);

    // localKV[:,0:256] = local @ Wk[:256,:]; localKV[:,256:512] = local @ Wv[:256,:]  (bf16)
    gemm_kernel<false, false, false, false, bf16><<<dim3(SIZE/64, NN/64), blk, 0, stream>>>(
        bufA, Wk, nullptr, nullptr, localKV, NN, HA, SIZE, 512);
    gemm_kernel<false, false, false, false, bf16><<<dim3(SIZE/64, NN/64), blk, 0, stream>>>(
        bufA, Wv, nullptr, nullptr, localKV + 256, NN, HA, SIZE, 512);

    // q = features@Wq + bq ; qproj = features@Wqp + bqp
    gemm_kernel<false, true,  false, false, float><<<dim3(SIZE/64, NN/64), blk, 0, stream>>>(
        features, Wq, bq, nullptr, qbuf, NN, HA, SIZE, HA);
    gemm_kernel<false, true,  false, false, float><<<dim3(HIDDEN/64, NN/64), blk, 0, stream>>>(
        features, Wqp, bqp, nullptr, bufB, NN, 512, SIZE, 512);

    // attention -> o (into bufA, local no longer needed)
    attn_kernel<<<dim3(NN), blk, 0, stream>>>(
        qbuf, bufB, localKV, dist, structure, Wv, bv, bufA);

    // out = o @ Wo + bo + features
    gemm_kernel<false, true,  false, true, float><<<dim3(SIZE/64, NN/64), blk, 0, stream>>>(
        bufA, Wo, bo, features, out, NN, SIZE, HA, SIZE);
}

// Round 3
// 277.902 us; speedup vs baseline: 1.3719x; 1.2277x over previous
//
#include <hip/hip_runtime.h>
#include <hip/hip_bf16.h>

#define NN 16384
#define SIZE 256
#define DISTD 64
#define KNBR 16
#define HEADS 8
#define HIDDEN 512
#define HA 256

typedef __bf16 bf16;
typedef bf16 bf16x8 __attribute__((ext_vector_type(8)));
typedef float f32x4 __attribute__((ext_vector_type(4)));

// ---------------------------------------------------------------------------
// bf16-MFMA GEMM: C[M,N] = act( relu_in?(A)[M,K] @ B[K,N] + bias + resid )
// A is AT (float or bf16) row-major stride K; B f32 [K,N]; C OutT stride ldc.
// ---------------------------------------------------------------------------
template<bool RELU_IN, bool BIAS, bool RELU_OUT, bool RESID, typename AT, typename OutT>
__global__ __launch_bounds__(256) void gemm_kernel(
    const AT* __restrict__ A, const float* __restrict__ B,
    const float* __restrict__ bias, const float* __restrict__ resid,
    OutT* __restrict__ C, int M, int N, int K, int ldc)
{
    __shared__ bf16 As[64][40];   // [row][k]
    __shared__ bf16 Bs[64][40];   // [col][k]

    const int t = threadIdx.x;
    const int w = t >> 6;
    const int l = t & 63;
    const int bm = blockIdx.y * 64;
    const int bn = blockIdx.x * 64;

    f32x4 acc[4] = {};

    const int ar = t >> 2;         // 0..63 (A row)
    const int ac = (t & 3) * 8;    // 0..24 (A k-col)
    const int br = t >> 3;         // 0..31 (B k-row)
    const int bc = (t & 7) * 8;    // 0..56 (B col)

    for (int k0 = 0; k0 < K; k0 += 32) {
        if constexpr (sizeof(AT) == 2) {
            const bf16* ap = (const bf16*)A + (long)(bm + ar) * K + k0 + ac;
            *(bf16x8*)&As[ar][ac] = *(const bf16x8*)ap;
        } else {
            const float* ap = (const float*)A + (long)(bm + ar) * K + k0 + ac;
            #pragma unroll
            for (int i = 0; i < 8; ++i) {
                float v = ap[i];
                if (RELU_IN) v = fmaxf(v, 0.f);
                As[ar][ac + i] = (bf16)v;
            }
        }
        const float* bp = B + (long)(k0 + br) * N + bn + bc;
        #pragma unroll
        for (int i = 0; i < 8; ++i) {
            Bs[bc + i][br] = (bf16)bp[i];
        }
        __syncthreads();

        bf16x8 afrag = *(const bf16x8*)&As[16 * w + (l & 15)][(l >> 4) * 8];
        #pragma unroll
        for (int nn = 0; nn < 4; ++nn) {
            bf16x8 bfrag = *(const bf16x8*)&Bs[nn * 16 + (l & 15)][(l >> 4) * 8];
            acc[nn] = __builtin_amdgcn_mfma_f32_16x16x32_bf16(afrag, bfrag, acc[nn], 0, 0, 0);
        }
        __syncthreads();
    }

    #pragma unroll
    for (int nn = 0; nn < 4; ++nn) {
        #pragma unroll
        for (int i = 0; i < 4; ++i) {
            int row = bm + 16 * w + (l >> 4) * 4 + i;
            int col = bn + nn * 16 + (l & 15);
            float v = acc[nn][i];
            if (BIAS) v += bias[col];
            if (RESID) v += resid[(long)row * N + col];
            if (RELU_OUT) v = fmaxf(v, 0.f);
            C[(long)row * ldc + col] = (OutT)v;
        }
    }
}

// ---------------------------------------------------------------------------
// Wqcat[c, 0:256] = Wq[c,:]; Wqcat[c, 256+h*64+d] = sum_a Wq[c,h32+a]*Wk[256+d,h32+a]
// ---------------------------------------------------------------------------
__global__ __launch_bounds__(256) void make_wqcat(const float* __restrict__ Wq,
                                                  const float* __restrict__ Wk,
                                                  float* __restrict__ Wqcat)
{
    int c = blockIdx.x, t = threadIdx.x;
    Wqcat[(long)c * 768 + t] = Wq[(long)c * 256 + t];
    #pragma unroll
    for (int r = 0; r < 2; ++r) {
        int hd = r * 256 + t;
        int h = hd >> 6, d = hd & 63;
        float s = 0.f;
        #pragma unroll
        for (int a = 0; a < 32; ++a)
            s += Wq[(long)c * 256 + h * 32 + a] * Wk[(long)(256 + d) * 256 + h * 32 + a];
        Wqcat[(long)c * 768 + 256 + hd] = s;
    }
}

__global__ __launch_bounds__(256) void make_bqcat(const float* __restrict__ bq,
                                                  const float* __restrict__ Wk,
                                                  float* __restrict__ bqcat)
{
    int t = threadIdx.x;
    bqcat[t] = bq[t];
    #pragma unroll
    for (int r = 0; r < 2; ++r) {
        int hd = r * 256 + t;
        int h = hd >> 6, d = hd & 63;
        float s = 0.f;
        #pragma unroll
        for (int a = 0; a < 32; ++a)
            s += bq[h * 32 + a] * Wk[(long)(256 + d) * 256 + h * 32 + a];
        bqcat[256 + hd] = s;
    }
}

// Wstack[0:256][c] = Wo; Wstack[256+h*64+d][c] = sum_a WvBot[d,h32+a]*Wo[h32+a,c]
__global__ __launch_bounds__(256) void make_wstack(const float* __restrict__ Wv,
                                                   const float* __restrict__ Wo,
                                                   float* __restrict__ Wstack)
{
    int r = blockIdx.x, t = threadIdx.x;
    if (r < 256) {
        Wstack[(long)r * 256 + t] = Wo[(long)r * 256 + t];
    } else {
        int hd = r - 256;
        int h = hd >> 6, d = hd & 63;
        float s = 0.f;
        #pragma unroll
        for (int a = 0; a < 32; ++a)
            s += Wv[(long)(256 + d) * 256 + h * 32 + a] * Wo[(long)(h * 32 + a) * 256 + t];
        Wstack[(long)r * 256 + t] = s;
    }
}

// biaso[c] = bo[c] + sum_u bv[u]*Wo[u,c]
__global__ __launch_bounds__(256) void make_biaso(const float* __restrict__ bo,
                                                  const float* __restrict__ bv,
                                                  const float* __restrict__ Wo,
                                                  float* __restrict__ biaso)
{
    int t = threadIdx.x;
    float s = bo[t];
    for (int u = 0; u < 256; ++u) s += bv[u] * Wo[(long)u * 256 + t];
    biaso[t] = s;
}

// ---------------------------------------------------------------------------
// Attention: one block per node. thread = (h = t>>5, j = (t>>1)&15, part = t&1)
//  score[h,j] = (q[h,:]·K[s_j][h,:] + dist[j,:]·qp[h,:]) * scale
//  concat[n] = [ o(256) | wd(512) ]  (bf16)
//    o[t]  = sum_j attn[h,j] * V[s_j][t]
//    wd[h*64+d] = sum_j attn[h,j] * dist[j,d]
// ---------------------------------------------------------------------------
__global__ __launch_bounds__(256) void attn_kernel(
    const bf16* __restrict__ qcat,      // [NN, 768]  (q | qproj)
    const bf16* __restrict__ localKV,   // [NN, 512]  (K | V)
    const float* __restrict__ dist,     // [NN, 16, 64]
    const int*  __restrict__ structure, // [NN, 16]
    bf16* __restrict__ concat)          // [NN, 768]
{
    const int n = blockIdx.x;
    const int t = threadIdx.x;
    const int h = t >> 5, j = (t >> 1) & 15, part = t & 1;

    __shared__ float dist_s[16][65];   // stride 65: conflict-free patterns
    __shared__ bf16  V_s[16][264];     // stride 264 bf16 (132 words)
    __shared__ float attn_s[8][16];
    __shared__ int   s_s[16];

    // ---- phase A: coalesced dist staging + structure
    {
        const float* dp = dist + (long)n * (KNBR * DISTD);
        #pragma unroll
        for (int i = 0; i < 4; ++i) {
            int e = i * 256 + t;
            dist_s[e >> 6][e & 63] = dp[e];
        }
    }
    if (t < 16) s_s[t] = structure[(long)n * KNBR + t];
    __syncthreads();

    // ---- phase B: V->LDS staging, K/q/qp -> regs, scores, softmax
    #pragma unroll
    for (int pass = 0; pass < 2; ++pass) {
        int idx = pass * 256 + t;
        int row = idx >> 5, chunk = idx & 31;
        bf16x8 v = *(const bf16x8*)(localKV + (long)s_s[row] * 512 + 256 + chunk * 8);
        *(bf16x8*)&V_s[row][chunk * 8] = v;
    }

    const bf16* qp_q = qcat + (long)n * 768 + h * 32 + part * 16;
    bf16x8 qa = *(const bf16x8*)qp_q;
    bf16x8 qb = *(const bf16x8*)(qp_q + 8);
    const bf16* qp_p = qcat + (long)n * 768 + 256 + h * 64 + part * 32;
    bf16x8 p0 = *(const bf16x8*)qp_p;
    bf16x8 p1 = *(const bf16x8*)(qp_p + 8);
    bf16x8 p2 = *(const bf16x8*)(qp_p + 16);
    bf16x8 p3 = *(const bf16x8*)(qp_p + 24);
    const bf16* kp = localKV + (long)s_s[j] * 512 + h * 32 + part * 16;
    bf16x8 ka = *(const bf16x8*)kp;
    bf16x8 kb = *(const bf16x8*)(kp + 8);

    float sc = 0.f;
    #pragma unroll
    for (int i = 0; i < 8; ++i)
        sc += (float)qa[i] * (float)ka[i] + (float)qb[i] * (float)kb[i];

    const int dbase = part * 32;
    #pragma unroll
    for (int i = 0; i < 8; ++i) sc += dist_s[j][dbase + i]      * (float)p0[i];
    #pragma unroll
    for (int i = 0; i < 8; ++i) sc += dist_s[j][dbase + 8 + i]  * (float)p1[i];
    #pragma unroll
    for (int i = 0; i < 8; ++i) sc += dist_s[j][dbase + 16 + i] * (float)p2[i];
    #pragma unroll
    for (int i = 0; i < 8; ++i) sc += dist_s[j][dbase + 24 + i] * (float)p3[i];

    sc += __shfl_xor(sc, 1);                    // combine parts: full score
    float s = sc * 0.17677669529663687f;        // 1/sqrt(32)
    float m = s;
    m = fmaxf(m, __shfl_xor(m, 2));
    m = fmaxf(m, __shfl_xor(m, 4));
    m = fmaxf(m, __shfl_xor(m, 8));
    m = fmaxf(m, __shfl_xor(m, 16));
    float e = __expf(s - m);
    float sum = e;
    sum += __shfl_xor(sum, 2);
    sum += __shfl_xor(sum, 4);
    sum += __shfl_xor(sum, 8);
    sum += __shfl_xor(sum, 16);
    float attn = e / sum;
    if (!part) attn_s[h][j] = attn;
    __syncthreads();

    // ---- phase C: outputs
    float acc = 0.f;
    #pragma unroll
    for (int j2 = 0; j2 < 16; ++j2)
        acc += attn_s[h][j2] * (float)V_s[j2][t];
    concat[(long)n * 768 + t] = (bf16)acc;

    #pragma unroll
    for (int rep = 0; rep < 2; ++rep) {
        int idx = rep * 256 + t;
        int h3 = idx >> 6, d3 = idx & 63;
        float s2 = 0.f;
        #pragma unroll
        for (int j2 = 0; j2 < 16; ++j2)
            s2 += attn_s[h3][j2] * dist_s[j2][d3];
        concat[(long)n * 768 + 256 + idx] = (bf16)s2;
    }
}

// ---------------------------------------------------------------------------
extern "C" void kernel_launch(void* const* d_in, const int* in_sizes, int n_in,
                              void* d_out, int out_size, void* d_ws, size_t ws_size,
                              hipStream_t stream)
{
    const float* features = (const float*)d_in[0];
    const float* dist     = (const float*)d_in[1];
    const int*   structure= (const int*)d_in[2];
    const float* W0 = (const float*)d_in[3];
    const float* b0 = (const float*)d_in[4];
    const float* W1 = (const float*)d_in[5];
    const float* b1 = (const float*)d_in[6];
    const float* W2 = (const float*)d_in[7];
    const float* b2 = (const float*)d_in[8];
    const float* Wq = (const float*)d_in[9];
    const float* bq = (const float*)d_in[10];
    const float* Wk = (const float*)d_in[11];
    // d_in[12] = bk : dropped exactly (softmax-invariant per-head shift)
    const float* Wv = (const float*)d_in[13];
    const float* bv = (const float*)d_in[14];
    const float* Wo = (const float*)d_in[15];
    const float* bo = (const float*)d_in[16];
    float* out = (float*)d_out;

    const size_t MB = 1u << 20;
    char* w = (char*)d_ws;
    float* bufA_f  = (float*)w;                 // [0,32MB)  H0 f32 [N,512]
    bf16*  local_b = (bf16*)w;                  // [0,8MB)   local bf16 [N,256] (over dead H0)
    bf16*  qcat    = (bf16*)(w + 8 * MB);       // [8,32MB)  qcat bf16 [N,768]
    float* bufB_f  = (float*)(w + 32 * MB);     // [32,64MB) H1 f32 [N,512]
    bf16*  concat  = (bf16*)(w + 32 * MB);      // [32,56MB) concat bf16 [N,768] (over dead H1)
    bf16*  localKV = (bf16*)(w + 64 * MB);      // [64,80MB) bf16 [N,512]
    float* Wqcat   = (float*)(w + 80 * MB);     // 256x768 f32
    float* Wstack  = Wqcat + 256 * 768;         // 768x256 f32
    float* bqcat   = Wstack + 768 * 256;        // 768
    float* biaso   = bqcat + 768;               // 256

    dim3 blk(256);

    make_wqcat<<<dim3(256), blk, 0, stream>>>(Wq, Wk, Wqcat);
    make_bqcat<<<dim3(1),   blk, 0, stream>>>(bq, Wk, bqcat);
    make_wstack<<<dim3(768), blk, 0, stream>>>(Wv, Wo, Wstack);
    make_biaso<<<dim3(1),   blk, 0, stream>>>(bo, bv, Wo, biaso);

    // MLP
    gemm_kernel<true,  true, true,  false, float, float><<<dim3(8, 256), blk, 0, stream>>>(
        features, W0, b0, nullptr, bufA_f, NN, HIDDEN, SIZE, HIDDEN);
    gemm_kernel<false, true, true,  false, float, float><<<dim3(8, 256), blk, 0, stream>>>(
        bufA_f, W1, b1, nullptr, bufB_f, NN, HIDDEN, HIDDEN, HIDDEN);
    gemm_kernel<false, true, true,  false, float, bf16><<<dim3(4, 256), blk, 0, stream>>>(
        bufB_f, W2, b2, nullptr, local_b, NN, SIZE, HIDDEN, SIZE);

    // qcat = features @ [Wq|Wqp] + [bq|bqp]   (bf16 out)
    gemm_kernel<false, true, false, false, float, bf16><<<dim3(12, 256), blk, 0, stream>>>(
        features, Wqcat, bqcat, nullptr, qcat, NN, 768, SIZE, 768);

    // localKV = local @ [Wk_top | Wv_top]  (bf16, interleaved rows)
    gemm_kernel<false, false, false, false, bf16, bf16><<<dim3(4, 256), blk, 0, stream>>>(
        local_b, Wk, nullptr, nullptr, localKV, NN, HA, SIZE, 512);
    gemm_kernel<false, false, false, false, bf16, bf16><<<dim3(4, 256), blk, 0, stream>>>(
        local_b, Wv, nullptr, nullptr, localKV + 256, NN, HA, SIZE, 512);

    attn_kernel<<<dim3(NN), blk, 0, stream>>>(qcat, localKV, dist, structure, concat);

    // out = concat @ [Wo ; U] + (bo + bv@Wo) + features
    gemm_kernel<false, true, false, true, bf16, float><<<dim3(4, 256), blk, 0, stream>>>(
        concat, Wstack, biaso, features, out, NN, SIZE, 768, SIZE);
}

// Round 4
// 176.005 us; speedup vs baseline: 2.1662x; 1.5789x over previous
//
#include <hip/hip_runtime.h>
#include <hip/hip_bf16.h>

#define NN 16384
#define SIZE 256
#define DISTD 64
#define KNBR 16
#define HEADS 8
#define HIDDEN 512
#define HA 256

typedef __bf16 bf16;
typedef bf16 bf16x4 __attribute__((ext_vector_type(4)));
typedef bf16 bf16x8 __attribute__((ext_vector_type(8)));
typedef float f32x4 __attribute__((ext_vector_type(4)));

__device__ __forceinline__ void gload16(const void* g, void* l) {
    __builtin_amdgcn_global_load_lds(
        (const __attribute__((address_space(1))) unsigned int*)g,
        (__attribute__((address_space(3))) unsigned int*)l, 16, 0, 0);
}

// ---------------------------------------------------------------------------
// m97-structure GEMM: C[M,N] = act(A[M,K]@B[K,N] + bias + resid)
// A bf16 [M,K] row-major; BT bf16 [N,K] row-major (B transposed).
// 128x128 tile, BK=32, 4 waves (2x2 of 64x64), global_load_lds staging.
// ---------------------------------------------------------------------------
template<bool BIAS, bool RELU_OUT, bool RESID, typename OutT>
__global__ __launch_bounds__(256) void gemm128(
    const bf16* __restrict__ A, const bf16* __restrict__ BT,
    const float* __restrict__ bias, const float* __restrict__ resid,
    OutT* __restrict__ C, int M, int N, int K)
{
    __shared__ alignas(16) bf16 As[128][32];
    __shared__ alignas(16) bf16 Bs[128][32];

    const int t = threadIdx.x;
    const int w = t >> 6, l = t & 63;
    const int bm = blockIdx.y * 128, bn = blockIdx.x * 128;
    const int wr = (w >> 1) * 64, wc = (w & 1) * 64;

    f32x4 acc[4][4] = {};

    // staging: thread t loads 16B at row (t>>2) [+64], col (t&3)*8
    const bf16* ag = A  + (size_t)(bm + (t >> 2)) * K + (t & 3) * 8;
    const bf16* bg = BT + (size_t)(bn + (t >> 2)) * K + (t & 3) * 8;
    bf16* asl = &As[w << 4][0];   // wave-uniform LDS dest base
    bf16* bsl = &Bs[w << 4][0];

    for (int k0 = 0; k0 < K; k0 += 32) {
        gload16(ag + k0, asl);
        gload16(ag + k0 + (size_t)64 * K, (char*)asl + 4096);
        gload16(bg + k0, bsl);
        gload16(bg + k0 + (size_t)64 * K, (char*)bsl + 4096);
        __syncthreads();

        bf16x8 af[4], bfr[4];
        #pragma unroll
        for (int m = 0; m < 4; ++m)
            af[m] = *(const bf16x8*)&As[wr + m * 16 + (l & 15)][(l >> 4) * 8];
        #pragma unroll
        for (int n2 = 0; n2 < 4; ++n2)
            bfr[n2] = *(const bf16x8*)&Bs[wc + n2 * 16 + (l & 15)][(l >> 4) * 8];
        #pragma unroll
        for (int m = 0; m < 4; ++m)
            #pragma unroll
            for (int n2 = 0; n2 < 4; ++n2)
                acc[m][n2] = __builtin_amdgcn_mfma_f32_16x16x32_bf16(
                    af[m], bfr[n2], acc[m][n2], 0, 0, 0);
        __syncthreads();
    }

    #pragma unroll
    for (int m = 0; m < 4; ++m) {
        const int row = bm + wr + m * 16 + ((l >> 4) << 2);
        #pragma unroll
        for (int n2 = 0; n2 < 4; ++n2) {
            const int col = bn + wc + n2 * 16 + (l & 15);
            #pragma unroll
            for (int i = 0; i < 4; ++i) {
                float v = acc[m][n2][i];
                if (BIAS) v += bias[col];
                if (RESID) v += resid[(size_t)(row + i) * N + col];
                if (RELU_OUT) v = fmaxf(v, 0.f);
                C[(size_t)(row + i) * N + col] = (OutT)v;
            }
        }
    }
}

// ---------------------------------------------------------------------------
// features f32 -> bf16 (plain) and bf16 (relu'd), float4 vectorized
// ---------------------------------------------------------------------------
__global__ __launch_bounds__(256) void feat2bf(const float4* __restrict__ f,
                                               bf16x4* __restrict__ fbf,
                                               bf16x4* __restrict__ frbf)
{
    int id = blockIdx.x * 256 + threadIdx.x;   // over 1M float4 groups
    float4 v = f[id];
    bf16x4 a, r;
    a[0] = (bf16)v.x; a[1] = (bf16)v.y; a[2] = (bf16)v.z; a[3] = (bf16)v.w;
    r[0] = (bf16)fmaxf(v.x, 0.f); r[1] = (bf16)fmaxf(v.y, 0.f);
    r[2] = (bf16)fmaxf(v.z, 0.f); r[3] = (bf16)fmaxf(v.w, 0.f);
    fbf[id] = a; frbf[id] = r;
}

// ---------------------------------------------------------------------------
// One merged prep kernel: all weight transposes/casts + fused small algebra.
//  W0T[512][256], W1T[512][512], W2T[256][512], WkvT[512][256],
//  WqcatT[768][256] (q|qproj weights), WstackT[256][768] ([Wo;U]^T),
//  bqcat[768], biaso[256] = bo + bv@Wo
// ---------------------------------------------------------------------------
__global__ __launch_bounds__(256) void prep_weights(
    const float* __restrict__ W0, const float* __restrict__ W1,
    const float* __restrict__ W2, const float* __restrict__ Wq,
    const float* __restrict__ bq, const float* __restrict__ Wk,
    const float* __restrict__ Wv, const float* __restrict__ Wo,
    const float* __restrict__ bo, const float* __restrict__ bv,
    bf16* __restrict__ W0T, bf16* __restrict__ W1T, bf16* __restrict__ W2T,
    bf16* __restrict__ WkvT, bf16* __restrict__ WqcatT, bf16* __restrict__ WstackT,
    float* __restrict__ bqcat, float* __restrict__ biaso)
{
    long id = blockIdx.x * 256L + threadIdx.x;
    if (id < 131072) {  // W0T[n][k] = W0[k][n], 512x256
        int n = id >> 8, k = id & 255;
        W0T[id] = (bf16)W0[(long)k * 512 + n]; return;
    }
    id -= 131072;
    if (id < 262144) {  // W1T[n][k] = W1[k][n], 512x512
        int n = id >> 9, k = id & 511;
        W1T[id] = (bf16)W1[(long)k * 512 + n]; return;
    }
    id -= 262144;
    if (id < 131072) {  // W2T[n][k] = W2[k][n], 256x512
        int n = id >> 9, k = id & 511;
        W2T[id] = (bf16)W2[(long)k * 256 + n]; return;
    }
    id -= 131072;
    if (id < 131072) {  // WkvT[n][k]: n<256 -> Wk top, else Wv top, 512x256
        int n = id >> 8, k = id & 255;
        WkvT[id] = (bf16)(n < 256 ? Wk[(long)k * 256 + n] : Wv[(long)k * 256 + (n - 256)]);
        return;
    }
    id -= 131072;
    if (id < 196608) {  // WqcatT[col][c], 768x256
        int col = id >> 8, c = id & 255;
        float s;
        if (col < 256) s = Wq[(long)c * 256 + col];
        else {
            int hd = col - 256, h = hd >> 6, d = hd & 63;
            s = 0.f;
            #pragma unroll
            for (int a = 0; a < 32; ++a)
                s += Wq[(long)c * 256 + h * 32 + a] * Wk[(long)(256 + d) * 256 + h * 32 + a];
        }
        WqcatT[id] = (bf16)s; return;
    }
    id -= 196608;
    if (id < 196608) {  // WstackT[col][r], 256x768
        int col = (int)(id / 768), r = (int)(id % 768);
        float s;
        if (r < 256) s = Wo[(long)r * 256 + col];
        else {
            int hd = r - 256, h = hd >> 6, d = hd & 63;
            s = 0.f;
            #pragma unroll
            for (int a = 0; a < 32; ++a)
                s += Wv[(long)(256 + d) * 256 + h * 32 + a] * Wo[(long)(h * 32 + a) * 256 + col];
        }
        WstackT[id] = (bf16)s; return;
    }
    id -= 196608;
    if (id < 768) {     // bqcat
        float s;
        if (id < 256) s = bq[id];
        else {
            int hd = (int)id - 256, h = hd >> 6, d = hd & 63;
            s = 0.f;
            #pragma unroll
            for (int a = 0; a < 32; ++a)
                s += bq[h * 32 + a] * Wk[(long)(256 + d) * 256 + h * 32 + a];
        }
        bqcat[id] = s; return;
    }
    id -= 768;
    if (id < 256) {     // biaso = bo + bv @ Wo
        float s = bo[id];
        for (int u = 0; u < 256; ++u) s += bv[u] * Wo[(long)u * 256 + id];
        biaso[id] = s;
    }
}

// ---------------------------------------------------------------------------
// Attention (unchanged from round 3): one block per node.
// ---------------------------------------------------------------------------
__global__ __launch_bounds__(256) void attn_kernel(
    const bf16* __restrict__ qcat,      // [NN, 768]  (q | qproj)
    const bf16* __restrict__ localKV,   // [NN, 512]  (K | V)
    const float* __restrict__ dist,     // [NN, 16, 64]
    const int*  __restrict__ structure, // [NN, 16]
    bf16* __restrict__ concat)          // [NN, 768]
{
    const int n = blockIdx.x;
    const int t = threadIdx.x;
    const int h = t >> 5, j = (t >> 1) & 15, part = t & 1;

    __shared__ float dist_s[16][65];
    __shared__ bf16  V_s[16][264];
    __shared__ float attn_s[8][16];
    __shared__ int   s_s[16];

    {
        const float* dp = dist + (long)n * (KNBR * DISTD);
        #pragma unroll
        for (int i = 0; i < 4; ++i) {
            int e = i * 256 + t;
            dist_s[e >> 6][e & 63] = dp[e];
        }
    }
    if (t < 16) s_s[t] = structure[(long)n * KNBR + t];
    __syncthreads();

    #pragma unroll
    for (int pass = 0; pass < 2; ++pass) {
        int idx = pass * 256 + t;
        int row = idx >> 5, chunk = idx & 31;
        bf16x8 v = *(const bf16x8*)(localKV + (long)s_s[row] * 512 + 256 + chunk * 8);
        *(bf16x8*)&V_s[row][chunk * 8] = v;
    }

    const bf16* qp_q = qcat + (long)n * 768 + h * 32 + part * 16;
    bf16x8 qa = *(const bf16x8*)qp_q;
    bf16x8 qb = *(const bf16x8*)(qp_q + 8);
    const bf16* qp_p = qcat + (long)n * 768 + 256 + h * 64 + part * 32;
    bf16x8 p0 = *(const bf16x8*)qp_p;
    bf16x8 p1 = *(const bf16x8*)(qp_p + 8);
    bf16x8 p2 = *(const bf16x8*)(qp_p + 16);
    bf16x8 p3 = *(const bf16x8*)(qp_p + 24);
    const bf16* kp = localKV + (long)s_s[j] * 512 + h * 32 + part * 16;
    bf16x8 ka = *(const bf16x8*)kp;
    bf16x8 kb = *(const bf16x8*)(kp + 8);

    float sc = 0.f;
    #pragma unroll
    for (int i = 0; i < 8; ++i)
        sc += (float)qa[i] * (float)ka[i] + (float)qb[i] * (float)kb[i];

    const int dbase = part * 32;
    #pragma unroll
    for (int i = 0; i < 8; ++i) sc += dist_s[j][dbase + i]      * (float)p0[i];
    #pragma unroll
    for (int i = 0; i < 8; ++i) sc += dist_s[j][dbase + 8 + i]  * (float)p1[i];
    #pragma unroll
    for (int i = 0; i < 8; ++i) sc += dist_s[j][dbase + 16 + i] * (float)p2[i];
    #pragma unroll
    for (int i = 0; i < 8; ++i) sc += dist_s[j][dbase + 24 + i] * (float)p3[i];

    sc += __shfl_xor(sc, 1);
    float s = sc * 0.17677669529663687f;
    float m = s;
    m = fmaxf(m, __shfl_xor(m, 2));
    m = fmaxf(m, __shfl_xor(m, 4));
    m = fmaxf(m, __shfl_xor(m, 8));
    m = fmaxf(m, __shfl_xor(m, 16));
    float e = __expf(s - m);
    float sum = e;
    sum += __shfl_xor(sum, 2);
    sum += __shfl_xor(sum, 4);
    sum += __shfl_xor(sum, 8);
    sum += __shfl_xor(sum, 16);
    float attn = e / sum;
    if (!part) attn_s[h][j] = attn;
    __syncthreads();

    float acc = 0.f;
    #pragma unroll
    for (int j2 = 0; j2 < 16; ++j2)
        acc += attn_s[h][j2] * (float)V_s[j2][t];
    concat[(long)n * 768 + t] = (bf16)acc;

    #pragma unroll
    for (int rep = 0; rep < 2; ++rep) {
        int idx = rep * 256 + t;
        int h3 = idx >> 6, d3 = idx & 63;
        float s2 = 0.f;
        #pragma unroll
        for (int j2 = 0; j2 < 16; ++j2)
            s2 += attn_s[h3][j2] * dist_s[j2][d3];
        concat[(long)n * 768 + 256 + idx] = (bf16)s2;
    }
}

// ---------------------------------------------------------------------------
extern "C" void kernel_launch(void* const* d_in, const int* in_sizes, int n_in,
                              void* d_out, int out_size, void* d_ws, size_t ws_size,
                              hipStream_t stream)
{
    const float* features = (const float*)d_in[0];
    const float* dist     = (const float*)d_in[1];
    const int*   structure= (const int*)d_in[2];
    const float* W0 = (const float*)d_in[3];
    const float* b0 = (const float*)d_in[4];
    const float* W1 = (const float*)d_in[5];
    const float* b1 = (const float*)d_in[6];
    const float* W2 = (const float*)d_in[7];
    const float* b2 = (const float*)d_in[8];
    const float* Wq = (const float*)d_in[9];
    const float* bq = (const float*)d_in[10];
    const float* Wk = (const float*)d_in[11];
    // d_in[12] = bk : dropped exactly (softmax-invariant per-head shift)
    const float* Wv = (const float*)d_in[13];
    const float* bv = (const float*)d_in[14];
    const float* Wo = (const float*)d_in[15];
    const float* bo = (const float*)d_in[16];
    float* out = (float*)d_out;

    const size_t MB = 1u << 20;
    char* w = (char*)d_ws;
    bf16*  fbf     = (bf16*)(w + 0 * MB);    // [0,8)    features bf16 [N,256]
    bf16*  frbf    = (bf16*)(w + 8 * MB);    // [8,16)   relu(features) bf16; dead after G1
    bf16*  local_b = (bf16*)(w + 8 * MB);    //          local bf16 [N,256] (over frbf)
    bf16*  H0      = (bf16*)(w + 16 * MB);   // [16,32)  H0 bf16 [N,512]; dead after G2
    bf16*  qcat    = (bf16*)(w + 16 * MB);   // [16,40)  qcat bf16 [N,768] (over H0)
    bf16*  H1      = (bf16*)(w + 32 * MB);   // [32,48)  H1 bf16 [N,512]; dead after G3
    bf16*  localKV = (bf16*)(w + 40 * MB);   // [40,56)  bf16 [N,512]
    bf16*  concat  = (bf16*)(w + 56 * MB);   // [56,80)  bf16 [N,768]
    char*  wb      = w + 80 * MB;            // weight area
    bf16*  W0T     = (bf16*)(wb + 0);
    bf16*  W1T     = (bf16*)(wb + 262144);
    bf16*  W2T     = (bf16*)(wb + 786432);
    bf16*  WkvT    = (bf16*)(wb + 1048576);
    bf16*  WqcatT  = (bf16*)(wb + 1310720);
    bf16*  WstackT = (bf16*)(wb + 1703936);
    float* bqcat   = (float*)(wb + 2097152);
    float* biaso   = (float*)(wb + 2100224);

    dim3 blk(256);

    feat2bf<<<dim3(4096), blk, 0, stream>>>((const float4*)features, (bf16x4*)fbf, (bf16x4*)frbf);
    prep_weights<<<dim3(4100), blk, 0, stream>>>(
        W0, W1, W2, Wq, bq, Wk, Wv, Wo, bo, bv,
        W0T, W1T, W2T, WkvT, WqcatT, WstackT, bqcat, biaso);

    // MLP
    gemm128<true,  true,  false, bf16><<<dim3(4, 128), blk, 0, stream>>>(
        frbf, W0T, b0, nullptr, H0, NN, 512, 256);
    gemm128<true,  true,  false, bf16><<<dim3(4, 128), blk, 0, stream>>>(
        H0, W1T, b1, nullptr, H1, NN, 512, 512);
    gemm128<true,  true,  false, bf16><<<dim3(2, 128), blk, 0, stream>>>(
        H1, W2T, b2, nullptr, local_b, NN, 256, 512);

    // qcat = features @ [Wq|Wqp] + [bq|bqp]
    gemm128<true,  false, false, bf16><<<dim3(6, 128), blk, 0, stream>>>(
        fbf, WqcatT, bqcat, nullptr, qcat, NN, 768, 256);

    // localKV = local @ [Wk_top | Wv_top]
    gemm128<false, false, false, bf16><<<dim3(4, 128), blk, 0, stream>>>(
        local_b, WkvT, nullptr, nullptr, localKV, NN, 512, 256);

    attn_kernel<<<dim3(NN), blk, 0, stream>>>(qcat, localKV, dist, structure, concat);

    // out = concat @ [Wo ; U] + (bo + bv@Wo) + features
    gemm128<true,  false, true,  float><<<dim3(2, 128), blk, 0, stream>>>(
        concat, WstackT, biaso, features, out, NN, 256, 768);
}

// Round 5
// 168.472 us; speedup vs baseline: 2.2631x; 1.0447x over previous
//
#include <hip/hip_runtime.h>
#include <hip/hip_bf16.h>

#define NN 16384
#define SIZE 256
#define DISTD 64
#define KNBR 16
#define HEADS 8
#define HIDDEN 512
#define HA 256

typedef __bf16 bf16;
typedef bf16 bf16x4 __attribute__((ext_vector_type(4)));
typedef bf16 bf16x8 __attribute__((ext_vector_type(8)));
typedef float f32x4 __attribute__((ext_vector_type(4)));

__device__ __forceinline__ void gload16(const void* g, void* l) {
    __builtin_amdgcn_global_load_lds(
        (const __attribute__((address_space(1))) unsigned int*)g,
        (__attribute__((address_space(3))) unsigned int*)l, 16, 0, 0);
}

// ---------------------------------------------------------------------------
// m97-structure GEMM + 2-phase double-buffered prefetch (T3 minimal recipe):
// stage tile t+1 BEFORE computing tile t; single barrier per iter.
// C[M,N] = act(A[M,K]@B[K,N] + bias + resid)
// A bf16 [M,K] row-major; BT bf16 [N,K] row-major (B transposed).
// 128x128 tile, BK=32, 4 waves (2x2 of 64x64).
// ---------------------------------------------------------------------------
template<bool BIAS, bool RELU_OUT, bool RESID, typename OutT>
__global__ __launch_bounds__(256) void gemm128(
    const bf16* __restrict__ A, const bf16* __restrict__ BT,
    const float* __restrict__ bias, const float* __restrict__ resid,
    OutT* __restrict__ C, int M, int N, int K)
{
    __shared__ alignas(16) bf16 As[2][128][32];
    __shared__ alignas(16) bf16 Bs[2][128][32];

    const int t = threadIdx.x;
    const int w = t >> 6, l = t & 63;
    const int bm = blockIdx.y * 128, bn = blockIdx.x * 128;
    const int wr = (w >> 1) * 64, wc = (w & 1) * 64;

    f32x4 acc[4][4] = {};

    // staging: thread t loads 16B at row (t>>2) [+64], col (t&3)*8
    // LDS layout is linear in t (wave-uniform base + lane*16B).
    const bf16* ag = A  + (size_t)(bm + (t >> 2)) * K + (t & 3) * 8;
    const bf16* bg = BT + (size_t)(bn + (t >> 2)) * K + (t & 3) * 8;

    const int nt = K >> 5;

    // prologue: stage tile 0 into buf 0
    {
        bf16* asl = &As[0][w << 4][0];
        bf16* bsl = &Bs[0][w << 4][0];
        gload16(ag, asl);
        gload16(ag + (size_t)64 * K, (char*)asl + 4096);
        gload16(bg, bsl);
        gload16(bg + (size_t)64 * K, (char*)bsl + 4096);
    }
    __syncthreads();

    for (int tt = 0; tt < nt; ++tt) {
        const int cur = tt & 1;
        if (tt + 1 < nt) {
            const int k0 = (tt + 1) << 5;
            bf16* asl = &As[cur ^ 1][w << 4][0];
            bf16* bsl = &Bs[cur ^ 1][w << 4][0];
            gload16(ag + k0, asl);
            gload16(ag + k0 + (size_t)64 * K, (char*)asl + 4096);
            gload16(bg + k0, bsl);
            gload16(bg + k0 + (size_t)64 * K, (char*)bsl + 4096);
        }

        bf16x8 af[4], bfr[4];
        #pragma unroll
        for (int m = 0; m < 4; ++m)
            af[m] = *(const bf16x8*)&As[cur][wr + m * 16 + (l & 15)][(l >> 4) * 8];
        #pragma unroll
        for (int n2 = 0; n2 < 4; ++n2)
            bfr[n2] = *(const bf16x8*)&Bs[cur][wc + n2 * 16 + (l & 15)][(l >> 4) * 8];
        #pragma unroll
        for (int m = 0; m < 4; ++m)
            #pragma unroll
            for (int n2 = 0; n2 < 4; ++n2)
                acc[m][n2] = __builtin_amdgcn_mfma_f32_16x16x32_bf16(
                    af[m], bfr[n2], acc[m][n2], 0, 0, 0);

        // one barrier per iter: compiler emits vmcnt(0)+lgkmcnt(0) drain here,
        // AFTER the compute phase has covered the staging latency.
        __syncthreads();
    }

    #pragma unroll
    for (int m = 0; m < 4; ++m) {
        const int row = bm + wr + m * 16 + ((l >> 4) << 2);
        #pragma unroll
        for (int n2 = 0; n2 < 4; ++n2) {
            const int col = bn + wc + n2 * 16 + (l & 15);
            #pragma unroll
            for (int i = 0; i < 4; ++i) {
                float v = acc[m][n2][i];
                if (BIAS) v += bias[col];
                if (RESID) v += resid[(size_t)(row + i) * N + col];
                if (RELU_OUT) v = fmaxf(v, 0.f);
                C[(size_t)(row + i) * N + col] = (OutT)v;
            }
        }
    }
}

// ---------------------------------------------------------------------------
// features f32 -> bf16 (plain) and bf16 (relu'd), float4 vectorized
// ---------------------------------------------------------------------------
__global__ __launch_bounds__(256) void feat2bf(const float4* __restrict__ f,
                                               bf16x4* __restrict__ fbf,
                                               bf16x4* __restrict__ frbf)
{
    int id = blockIdx.x * 256 + threadIdx.x;   // over 1M float4 groups
    float4 v = f[id];
    bf16x4 a, r;
    a[0] = (bf16)v.x; a[1] = (bf16)v.y; a[2] = (bf16)v.z; a[3] = (bf16)v.w;
    r[0] = (bf16)fmaxf(v.x, 0.f); r[1] = (bf16)fmaxf(v.y, 0.f);
    r[2] = (bf16)fmaxf(v.z, 0.f); r[3] = (bf16)fmaxf(v.w, 0.f);
    fbf[id] = a; frbf[id] = r;
}

// ---------------------------------------------------------------------------
// One merged prep kernel: all weight transposes/casts + fused small algebra.
// ---------------------------------------------------------------------------
__global__ __launch_bounds__(256) void prep_weights(
    const float* __restrict__ W0, const float* __restrict__ W1,
    const float* __restrict__ W2, const float* __restrict__ Wq,
    const float* __restrict__ bq, const float* __restrict__ Wk,
    const float* __restrict__ Wv, const float* __restrict__ Wo,
    const float* __restrict__ bo, const float* __restrict__ bv,
    bf16* __restrict__ W0T, bf16* __restrict__ W1T, bf16* __restrict__ W2T,
    bf16* __restrict__ WkvT, bf16* __restrict__ WqcatT, bf16* __restrict__ WstackT,
    float* __restrict__ bqcat, float* __restrict__ biaso)
{
    long id = blockIdx.x * 256L + threadIdx.x;
    if (id < 131072) {  // W0T[n][k] = W0[k][n], 512x256
        int n = id >> 8, k = id & 255;
        W0T[id] = (bf16)W0[(long)k * 512 + n]; return;
    }
    id -= 131072;
    if (id < 262144) {  // W1T[n][k] = W1[k][n], 512x512
        int n = id >> 9, k = id & 511;
        W1T[id] = (bf16)W1[(long)k * 512 + n]; return;
    }
    id -= 262144;
    if (id < 131072) {  // W2T[n][k] = W2[k][n], 256x512
        int n = id >> 9, k = id & 511;
        W2T[id] = (bf16)W2[(long)k * 256 + n]; return;
    }
    id -= 131072;
    if (id < 131072) {  // WkvT[n][k]: n<256 -> Wk top, else Wv top, 512x256
        int n = id >> 8, k = id & 255;
        WkvT[id] = (bf16)(n < 256 ? Wk[(long)k * 256 + n] : Wv[(long)k * 256 + (n - 256)]);
        return;
    }
    id -= 131072;
    if (id < 196608) {  // WqcatT[col][c], 768x256
        int col = id >> 8, c = id & 255;
        float s;
        if (col < 256) s = Wq[(long)c * 256 + col];
        else {
            int hd = col - 256, h = hd >> 6, d = hd & 63;
            s = 0.f;
            #pragma unroll
            for (int a = 0; a < 32; ++a)
                s += Wq[(long)c * 256 + h * 32 + a] * Wk[(long)(256 + d) * 256 + h * 32 + a];
        }
        WqcatT[id] = (bf16)s; return;
    }
    id -= 196608;
    if (id < 196608) {  // WstackT[col][r], 256x768
        int col = (int)(id / 768), r = (int)(id % 768);
        float s;
        if (r < 256) s = Wo[(long)r * 256 + col];
        else {
            int hd = r - 256, h = hd >> 6, d = hd & 63;
            s = 0.f;
            #pragma unroll
            for (int a = 0; a < 32; ++a)
                s += Wv[(long)(256 + d) * 256 + h * 32 + a] * Wo[(long)(h * 32 + a) * 256 + col];
        }
        WstackT[id] = (bf16)s; return;
    }
    id -= 196608;
    if (id < 768) {     // bqcat
        float s;
        if (id < 256) s = bq[id];
        else {
            int hd = (int)id - 256, h = hd >> 6, d = hd & 63;
            s = 0.f;
            #pragma unroll
            for (int a = 0; a < 32; ++a)
                s += bq[h * 32 + a] * Wk[(long)(256 + d) * 256 + h * 32 + a];
        }
        bqcat[id] = s; return;
    }
    id -= 768;
    if (id < 256) {     // biaso = bo + bv @ Wo
        float s = bo[id];
        for (int u = 0; u < 256; ++u) s += bv[u] * Wo[(long)u * 256 + id];
        biaso[id] = s;
    }
}

// ---------------------------------------------------------------------------
// Attention (unchanged): one block per node.
// ---------------------------------------------------------------------------
__global__ __launch_bounds__(256) void attn_kernel(
    const bf16* __restrict__ qcat,      // [NN, 768]  (q | qproj)
    const bf16* __restrict__ localKV,   // [NN, 512]  (K | V)
    const float* __restrict__ dist,     // [NN, 16, 64]
    const int*  __restrict__ structure, // [NN, 16]
    bf16* __restrict__ concat)          // [NN, 768]
{
    const int n = blockIdx.x;
    const int t = threadIdx.x;
    const int h = t >> 5, j = (t >> 1) & 15, part = t & 1;

    __shared__ float dist_s[16][65];
    __shared__ bf16  V_s[16][264];
    __shared__ float attn_s[8][16];
    __shared__ int   s_s[16];

    {
        const float* dp = dist + (long)n * (KNBR * DISTD);
        #pragma unroll
        for (int i = 0; i < 4; ++i) {
            int e = i * 256 + t;
            dist_s[e >> 6][e & 63] = dp[e];
        }
    }
    if (t < 16) s_s[t] = structure[(long)n * KNBR + t];
    __syncthreads();

    #pragma unroll
    for (int pass = 0; pass < 2; ++pass) {
        int idx = pass * 256 + t;
        int row = idx >> 5, chunk = idx & 31;
        bf16x8 v = *(const bf16x8*)(localKV + (long)s_s[row] * 512 + 256 + chunk * 8);
        *(bf16x8*)&V_s[row][chunk * 8] = v;
    }

    const bf16* qp_q = qcat + (long)n * 768 + h * 32 + part * 16;
    bf16x8 qa = *(const bf16x8*)qp_q;
    bf16x8 qb = *(const bf16x8*)(qp_q + 8);
    const bf16* qp_p = qcat + (long)n * 768 + 256 + h * 64 + part * 32;
    bf16x8 p0 = *(const bf16x8*)qp_p;
    bf16x8 p1 = *(const bf16x8*)(qp_p + 8);
    bf16x8 p2 = *(const bf16x8*)(qp_p + 16);
    bf16x8 p3 = *(const bf16x8*)(qp_p + 24);
    const bf16* kp = localKV + (long)s_s[j] * 512 + h * 32 + part * 16;
    bf16x8 ka = *(const bf16x8*)kp;
    bf16x8 kb = *(const bf16x8*)(kp + 8);

    float sc = 0.f;
    #pragma unroll
    for (int i = 0; i < 8; ++i)
        sc += (float)qa[i] * (float)ka[i] + (float)qb[i] * (float)kb[i];

    const int dbase = part * 32;
    #pragma unroll
    for (int i = 0; i < 8; ++i) sc += dist_s[j][dbase + i]      * (float)p0[i];
    #pragma unroll
    for (int i = 0; i < 8; ++i) sc += dist_s[j][dbase + 8 + i]  * (float)p1[i];
    #pragma unroll
    for (int i = 0; i < 8; ++i) sc += dist_s[j][dbase + 16 + i] * (float)p2[i];
    #pragma unroll
    for (int i = 0; i < 8; ++i) sc += dist_s[j][dbase + 24 + i] * (float)p3[i];

    sc += __shfl_xor(sc, 1);
    float s = sc * 0.17677669529663687f;
    float m = s;
    m = fmaxf(m, __shfl_xor(m, 2));
    m = fmaxf(m, __shfl_xor(m, 4));
    m = fmaxf(m, __shfl_xor(m, 8));
    m = fmaxf(m, __shfl_xor(m, 16));
    float e = __expf(s - m);
    float sum = e;
    sum += __shfl_xor(sum, 2);
    sum += __shfl_xor(sum, 4);
    sum += __shfl_xor(sum, 8);
    sum += __shfl_xor(sum, 16);
    float attn = e / sum;
    if (!part) attn_s[h][j] = attn;
    __syncthreads();

    float acc = 0.f;
    #pragma unroll
    for (int j2 = 0; j2 < 16; ++j2)
        acc += attn_s[h][j2] * (float)V_s[j2][t];
    concat[(long)n * 768 + t] = (bf16)acc;

    #pragma unroll
    for (int rep = 0; rep < 2; ++rep) {
        int idx = rep * 256 + t;
        int h3 = idx >> 6, d3 = idx & 63;
        float s2 = 0.f;
        #pragma unroll
        for (int j2 = 0; j2 < 16; ++j2)
            s2 += attn_s[h3][j2] * dist_s[j2][d3];
        concat[(long)n * 768 + 256 + idx] = (bf16)s2;
    }
}

// ---------------------------------------------------------------------------
extern "C" void kernel_launch(void* const* d_in, const int* in_sizes, int n_in,
                              void* d_out, int out_size, void* d_ws, size_t ws_size,
                              hipStream_t stream)
{
    const float* features = (const float*)d_in[0];
    const float* dist     = (const float*)d_in[1];
    const int*   structure= (const int*)d_in[2];
    const float* W0 = (const float*)d_in[3];
    const float* b0 = (const float*)d_in[4];
    const float* W1 = (const float*)d_in[5];
    const float* b1 = (const float*)d_in[6];
    const float* W2 = (const float*)d_in[7];
    const float* b2 = (const float*)d_in[8];
    const float* Wq = (const float*)d_in[9];
    const float* bq = (const float*)d_in[10];
    const float* Wk = (const float*)d_in[11];
    // d_in[12] = bk : dropped exactly (softmax-invariant per-head shift)
    const float* Wv = (const float*)d_in[13];
    const float* bv = (const float*)d_in[14];
    const float* Wo = (const float*)d_in[15];
    const float* bo = (const float*)d_in[16];
    float* out = (float*)d_out;

    const size_t MB = 1u << 20;
    char* w = (char*)d_ws;
    bf16*  fbf     = (bf16*)(w + 0 * MB);    // [0,8)    features bf16 [N,256]
    bf16*  frbf    = (bf16*)(w + 8 * MB);    // [8,16)   relu(features) bf16; dead after G1
    bf16*  local_b = (bf16*)(w + 8 * MB);    //          local bf16 [N,256] (over frbf)
    bf16*  H0      = (bf16*)(w + 16 * MB);   // [16,32)  H0 bf16 [N,512]; dead after G2
    bf16*  qcat    = (bf16*)(w + 16 * MB);   // [16,40)  qcat bf16 [N,768] (over H0)
    bf16*  H1      = (bf16*)(w + 32 * MB);   // [32,48)  H1 bf16 [N,512]; dead after G3
    bf16*  localKV = (bf16*)(w + 40 * MB);   // [40,56)  bf16 [N,512]
    bf16*  concat  = (bf16*)(w + 56 * MB);   // [56,80)  bf16 [N,768]
    char*  wb      = w + 80 * MB;            // weight area
    bf16*  W0T     = (bf16*)(wb + 0);
    bf16*  W1T     = (bf16*)(wb + 262144);
    bf16*  W2T     = (bf16*)(wb + 786432);
    bf16*  WkvT    = (bf16*)(wb + 1048576);
    bf16*  WqcatT  = (bf16*)(wb + 1310720);
    bf16*  WstackT = (bf16*)(wb + 1703936);
    float* bqcat   = (float*)(wb + 2097152);
    float* biaso   = (float*)(wb + 2100224);

    dim3 blk(256);

    feat2bf<<<dim3(4096), blk, 0, stream>>>((const float4*)features, (bf16x4*)fbf, (bf16x4*)frbf);
    prep_weights<<<dim3(4100), blk, 0, stream>>>(
        W0, W1, W2, Wq, bq, Wk, Wv, Wo, bo, bv,
        W0T, W1T, W2T, WkvT, WqcatT, WstackT, bqcat, biaso);

    // MLP
    gemm128<true,  true,  false, bf16><<<dim3(4, 128), blk, 0, stream>>>(
        frbf, W0T, b0, nullptr, H0, NN, 512, 256);
    gemm128<true,  true,  false, bf16><<<dim3(4, 128), blk, 0, stream>>>(
        H0, W1T, b1, nullptr, H1, NN, 512, 512);
    gemm128<true,  true,  false, bf16><<<dim3(2, 128), blk, 0, stream>>>(
        H1, W2T, b2, nullptr, local_b, NN, 256, 512);

    // qcat = features @ [Wq|Wqp] + [bq|bqp]
    gemm128<true,  false, false, bf16><<<dim3(6, 128), blk, 0, stream>>>(
        fbf, WqcatT, bqcat, nullptr, qcat, NN, 768, 256);

    // localKV = local @ [Wk_top | Wv_top]
    gemm128<false, false, false, bf16><<<dim3(4, 128), blk, 0, stream>>>(
        local_b, WkvT, nullptr, nullptr, localKV, NN, 512, 256);

    attn_kernel<<<dim3(NN), blk, 0, stream>>>(qcat, localKV, dist, structure, concat);

    // out = concat @ [Wo ; U] + (bo + bv@Wo) + features
    gemm128<true,  false, true,  float><<<dim3(2, 128), blk, 0, stream>>>(
        concat, WstackT, biaso, features, out, NN, 256, 768);
}